// Round 4
// baseline (275.568 us; speedup 1.0000x reference)
//
#include <hip/hip_runtime.h>

#define NNODES 20000
#define BATCH  2
#define FEAT   256
#define OOUT   64
#define MROWS  (BATCH * NNODES)   // 40000
#define MPAD   40064              // 626 * 64
#define NBLK   1250               // node blocks per pair (16 nodes each)

typedef short  bhalf8 __attribute__((ext_vector_type(8)));   // 8 bf16 in 4 VGPRs
typedef float  floatx4 __attribute__((ext_vector_type(4)));

// ---------- bf16 helpers ----------
__device__ __forceinline__ float bf2f(unsigned short u) {
  return __uint_as_float(((unsigned int)u) << 16);
}
__device__ __forceinline__ unsigned short f2bf(float f) {  // round-to-nearest-even
  unsigned int u = __float_as_uint(f);
  return (unsigned short)((u + 0x7fffu + ((u >> 16) & 1u)) >> 16);
}

// ---------- detect edge dtype + zero cnt/fill (single block) ----------
__global__ __launch_bounds__(256) void detect_zero_kernel(const int* __restrict__ raw,
                                                          int* __restrict__ flag,
                                                          int* __restrict__ cnt,
                                                          int* __restrict__ fill, int E) {
  for (int i = threadIdx.x; i < NNODES; i += 256) { cnt[i] = 0; fill[i] = 0; }
  __shared__ int any;
  if (threadIdx.x == 0) any = 0;
  __syncthreads();
  int nchk = E < 2048 ? E : 2048;
  for (int i = threadIdx.x; i < nchk; i += blockDim.x)
    if (raw[2 * i + 1] != 0) any = 1;   // int64 high words are 0 (values < 20000)
  __syncthreads();
  if (threadIdx.x == 0) *flag = any;    // 1 => int32 layout, 0 => int64 layout
}

// ---------- convert + degree count ----------
__global__ void convert_count_kernel(const int* __restrict__ raw, const int* __restrict__ flag,
                                     int* __restrict__ s32, int* __restrict__ d32,
                                     int* __restrict__ cnt, int E) {
  int e = blockIdx.x * blockDim.x + threadIdx.x;
  if (e >= E) return;
  int s, d;
  if (*flag) { s = raw[e];     d = raw[E + e]; }
  else       { s = raw[2 * e]; d = raw[2 * (E + e)]; }
  s32[e] = s; d32[e] = d;
  atomicAdd(&cnt[d], 1);
}

// single-block scan over counts -> exclusive row_start; also computes dinv
__global__ __launch_bounds__(1024) void scan_dinv_kernel(const int* __restrict__ cnt,
                                                         int* __restrict__ row_start,
                                                         float* __restrict__ dinv, int n) {
  __shared__ int wsum[16];
  __shared__ int carry_s;
  int tid = threadIdx.x, lane = tid & 63, wv = tid >> 6;
  if (tid == 0) carry_s = 0;
  __syncthreads();
  for (int base = 0; base < n; base += 1024) {
    int v = (base + tid < n) ? cnt[base + tid] : 0;
    if (base + tid < n) dinv[base + tid] = 1.0f / sqrtf((float)(v + 1));
    int x = v;                              // inclusive wave scan
#pragma unroll
    for (int off = 1; off < 64; off <<= 1) {
      int t = __shfl_up(x, off);
      if (lane >= off) x += t;
    }
    if (lane == 63) wsum[wv] = x;
    __syncthreads();
    int carry = carry_s;
    if (wv == 0) {
      int s = (lane < 16) ? wsum[lane] : 0;
#pragma unroll
      for (int off = 1; off < 16; off <<= 1) {
        int t = __shfl_up(s, off);
        if (lane >= off) s += t;
      }
      if (lane < 16) wsum[lane] = s;
    }
    __syncthreads();
    int woff = wv ? wsum[wv - 1] : 0;
    int total = wsum[15];
    if (base + tid < n) row_start[base + tid] = carry + woff + x - v;
    __syncthreads();
    if (tid == 0) carry_s = carry + total;
  }
  if (tid == 0) row_start[n] = carry_s;
}

__global__ void scatter_kernel(const int* __restrict__ s32, const int* __restrict__ d32,
                               const int* __restrict__ row_start, int* __restrict__ fill,
                               const float* __restrict__ dinv,
                               int* __restrict__ csr_src, float* __restrict__ csr_norm, int E) {
  int e = blockIdx.x * blockDim.x + threadIdx.x;
  if (e >= E) return;
  int s = s32[e], d = d32[e];
  int p = row_start[d] + atomicAdd(&fill[d], 1);
  csr_src[p] = s;
  csr_norm[p] = dinv[s] * dinv[d];
}

// ---------- W prep: fp32 W[k][n] -> bf16 hi/lo, MFMA fragment order; blocks 0-255 -> W1, 256-511 -> W2
__global__ __launch_bounds__(256) void wprep_kernel(const float* __restrict__ W1,
                                                    const float* __restrict__ W2,
                                                    unsigned short* __restrict__ W1hi,
                                                    unsigned short* __restrict__ W1lo,
                                                    unsigned short* __restrict__ W2hi,
                                                    unsigned short* __restrict__ W2lo) {
  int which = blockIdx.x >> 8;
  int idx = (blockIdx.x & 255) * 256 + threadIdx.x;   // idx = k*256 + n
  const float* W = which ? W2 : W1;
  unsigned short* Whi = which ? W2hi : W1hi;
  unsigned short* Wlo = which ? W2lo : W1lo;
  int k = idx >> 8, n = idx & 255;
  float w = W[idx];
  unsigned short hi = f2bf(w);
  unsigned short lo = f2bf(w - bf2f(hi));
  int g = n >> 4, ln = n & 15;
  int ks = k >> 5, ch = (k >> 3) & 3, j = k & 7;
  int addr = ((ks * 16 + g) * 64 + ch * 16 + ln) * 8 + j;
  Whi[addr] = hi;
  Wlo[addr] = lo;
}

// ---------- MFMA GEMM: C[M,256] = A[M,256] @ W, A fp32 (layer1) or bf16 (layer2) ----------
template <int AFP32>
__global__ __launch_bounds__(256) void gemm_mfma(const void* __restrict__ Av,
                                                 const unsigned short* __restrict__ Whi,
                                                 const unsigned short* __restrict__ Wlo,
                                                 unsigned short* __restrict__ C) {
  __shared__ unsigned short lds_arr[32768];   // 2 bufs x (hi 8192 + lo 8192) ushorts
  int tid = threadIdx.x, lane = tid & 63, wv = tid >> 6;
  int m0 = blockIdx.x * 64 + wv * 16;
  int mrow = m0 + (lane & 15);
  if (mrow >= MROWS) mrow = MROWS - 1;        // clamp pad rows (output ignored)
  int kc = (lane >> 4) * 8;                   // k-chunk offset within BK=32

  const float* Af          = (const float*)Av;
  const unsigned short* Ab = (const unsigned short*)Av;

  floatx4 acc[16];
#pragma unroll
  for (int g = 0; g < 16; ++g) acc[g] = (floatx4)(0.0f);

  bhalf8 st[8];  // staging regs: 4 hi + 4 lo chunks of 16B per thread

  auto stage_load = [&](int ks) {
#pragma unroll
    for (int i = 0; i < 4; ++i)
      st[i] = *(const bhalf8*)&Whi[(size_t)ks * 8192 + (i * 256 + tid) * 8];
#pragma unroll
    for (int i = 0; i < 4; ++i)
      st[4 + i] = *(const bhalf8*)&Wlo[(size_t)ks * 8192 + (i * 256 + tid) * 8];
  };
  auto stage_write = [&](int b) {
    unsigned short* base = &lds_arr[b * 16384];
#pragma unroll
    for (int i = 0; i < 4; ++i)
      *(bhalf8*)&base[(i * 256 + tid) * 8] = st[i];
#pragma unroll
    for (int i = 0; i < 4; ++i)
      *(bhalf8*)&base[8192 + (i * 256 + tid) * 8] = st[4 + i];
  };
  auto load_a = [&](int ks) -> bhalf8 {
    bhalf8 r;
    if (AFP32) {
      const float* p = &Af[(size_t)mrow * FEAT + ks * 32 + kc];
      float4 u = *(const float4*)p;
      float4 v = *(const float4*)(p + 4);
      r[0] = (short)f2bf(u.x); r[1] = (short)f2bf(u.y);
      r[2] = (short)f2bf(u.z); r[3] = (short)f2bf(u.w);
      r[4] = (short)f2bf(v.x); r[5] = (short)f2bf(v.y);
      r[6] = (short)f2bf(v.z); r[7] = (short)f2bf(v.w);
    } else {
      r = *(const bhalf8*)&Ab[(size_t)mrow * FEAT + ks * 32 + kc];
    }
    return r;
  };

  stage_load(0);
  stage_write(0);
  __syncthreads();
  int cur = 0;
  for (int ks = 0; ks < 8; ++ks) {
    if (ks < 7) stage_load(ks + 1);           // global loads in flight under compute
    bhalf8 a = load_a(ks);
    const unsigned short* bb = &lds_arr[cur * 16384];
#pragma unroll
    for (int g = 0; g < 16; ++g) {
      bhalf8 bh = *(const bhalf8*)&bb[g * 512 + lane * 8];          // contiguous: conflict-free
      bhalf8 bl = *(const bhalf8*)&bb[8192 + g * 512 + lane * 8];
      acc[g] = __builtin_amdgcn_mfma_f32_16x16x32_bf16(bh, a, acc[g], 0, 0, 0);
      acc[g] = __builtin_amdgcn_mfma_f32_16x16x32_bf16(bl, a, acc[g], 0, 0, 0);
    }
    if (ks < 7) stage_write(cur ^ 1);
    __syncthreads();
    cur ^= 1;
  }

  // D layout: m_local = lane&15, n_local = (lane>>4)*4 + reg
  int om = m0 + (lane & 15);                  // < MPAD, C is padded
  int nc = (lane >> 4) * 4;
#pragma unroll
  for (int g = 0; g < 16; ++g) {
    ushort4 o;
    o.x = f2bf(acc[g][0]); o.y = f2bf(acc[g][1]);
    o.z = f2bf(acc[g][2]); o.w = f2bf(acc[g][3]);
    *(ushort4*)&C[(size_t)om * FEAT + g * 16 + nc] = o;
  }
}

// ---------- aggregation, XCD-sliced: pair = blockIdx&7 = (chunk<<1)|batch ----------
// Each pair touches a 64-feat x 1-batch slice (2.56 MB, L2-resident per XCD).
// FINAL=0: out[b,n,c..] = bf16(relu(bias + dinv^2*h[n] + sum norm*h[src]))
// FINAL=1: per-block partial sums of relu(...) -> pp[pair][nb][64]
template <int FINAL>
__global__ __launch_bounds__(256) void agg_kernel(const unsigned short* __restrict__ h,
                                                  const int* __restrict__ row_start,
                                                  const int* __restrict__ csr_src,
                                                  const float* __restrict__ csr_norm,
                                                  const float* __restrict__ dinv,
                                                  const float* __restrict__ bias,
                                                  unsigned short* __restrict__ out,
                                                  float* __restrict__ pp) {
  int pair  = blockIdx.x & 7;          // -> XCD (round-robin dispatch)
  int nb    = blockIdx.x >> 3;         // node block [0, NBLK)
  int batch = pair & 1;
  int chunk = pair >> 1;               // 64-feat chunk [0,4)
  int tid = threadIdx.x;
  int grp = tid >> 4;                  // 16 node-groups per block
  int fl  = tid & 15;                  // feat lane (4 feats each)
  int n   = nb * 16 + grp;
  int c   = chunk * 64 + fl * 4;
  const unsigned short* hb = h + (size_t)batch * NNODES * FEAT;
  float di = dinv[n];
  float sn = di * di;
  ushort4 v = *(const ushort4*)&hb[(size_t)n * FEAT + c];
  float4 acc = make_float4(bf2f(v.x) * sn, bf2f(v.y) * sn, bf2f(v.z) * sn, bf2f(v.w) * sn);
  int s0 = row_start[n], s1 = row_start[n + 1];
  int i = s0;
  for (; i + 2 <= s1; i += 2) {
    int sa = csr_src[i], sb = csr_src[i + 1];
    float wa = csr_norm[i], wb = csr_norm[i + 1];
    ushort4 ma = *(const ushort4*)&hb[(size_t)sa * FEAT + c];
    ushort4 mb = *(const ushort4*)&hb[(size_t)sb * FEAT + c];
    acc.x = fmaf(wa, bf2f(ma.x), acc.x);
    acc.y = fmaf(wa, bf2f(ma.y), acc.y);
    acc.z = fmaf(wa, bf2f(ma.z), acc.z);
    acc.w = fmaf(wa, bf2f(ma.w), acc.w);
    acc.x = fmaf(wb, bf2f(mb.x), acc.x);
    acc.y = fmaf(wb, bf2f(mb.y), acc.y);
    acc.z = fmaf(wb, bf2f(mb.z), acc.z);
    acc.w = fmaf(wb, bf2f(mb.w), acc.w);
  }
  if (i < s1) {
    int s = csr_src[i];
    float w = csr_norm[i];
    ushort4 m = *(const ushort4*)&hb[(size_t)s * FEAT + c];
    acc.x = fmaf(w, bf2f(m.x), acc.x);
    acc.y = fmaf(w, bf2f(m.y), acc.y);
    acc.z = fmaf(w, bf2f(m.z), acc.z);
    acc.w = fmaf(w, bf2f(m.w), acc.w);
  }
  float4 bi = *(const float4*)&bias[c];
  float rx = fmaxf(acc.x + bi.x, 0.0f);
  float ry = fmaxf(acc.y + bi.y, 0.0f);
  float rz = fmaxf(acc.z + bi.z, 0.0f);
  float rw = fmaxf(acc.w + bi.w, 0.0f);
  if (!FINAL) {
    ushort4 o;
    o.x = f2bf(rx); o.y = f2bf(ry); o.z = f2bf(rz); o.w = f2bf(rw);
    *(ushort4*)&out[((size_t)batch * NNODES + n) * FEAT + c] = o;
  } else {
    // sum relu'd values over the block's 16 nodes -> one 64-float partial
    rx += __shfl_down(rx, 32); ry += __shfl_down(ry, 32);
    rz += __shfl_down(rz, 32); rw += __shfl_down(rw, 32);
    rx += __shfl_down(rx, 16); ry += __shfl_down(ry, 16);
    rz += __shfl_down(rz, 16); rw += __shfl_down(rw, 16);
    __shared__ float red[4][64];
    int wv = tid >> 6, lane = tid & 63;
    if (lane < 16) {
      red[wv][fl * 4 + 0] = rx; red[wv][fl * 4 + 1] = ry;
      red[wv][fl * 4 + 2] = rz; red[wv][fl * 4 + 3] = rw;
    }
    __syncthreads();
    if (tid < 64)
      pp[((size_t)pair * NBLK + nb) * 64 + tid] =
          red[0][tid] + red[1][tid] + red[2][tid] + red[3][tid];
  }
}

// ---------- reduce partials -> pooled[b][256] ----------
__global__ __launch_bounds__(256) void pool_reduce(const float* __restrict__ pp,
                                                   float* __restrict__ pooled) {
  int p = blockIdx.x >> 6, f = blockIdx.x & 63;
  float s = 0.f;
  for (int nb = threadIdx.x; nb < NBLK; nb += 256)
    s += pp[((size_t)p * NBLK + nb) * 64 + f];
#pragma unroll
  for (int off = 32; off >= 1; off >>= 1) s += __shfl_down(s, off);
  __shared__ float ws[4];
  if ((threadIdx.x & 63) == 0) ws[threadIdx.x >> 6] = s;
  __syncthreads();
  if (threadIdx.x == 0) {
    float t = ws[0] + ws[1] + ws[2] + ws[3];
    int batch = p & 1, chunk = p >> 1;
    pooled[batch * FEAT + chunk * 64 + f] = t / (float)NNODES;
  }
}

// ---------- final FC: out[b][o] = bfc[o] + pooled[b,:] . Wfc[:,o] ----------
__global__ __launch_bounds__(128) void fc_kernel(const float* __restrict__ pooled,
                                                 const float* __restrict__ Wfc,
                                                 const float* __restrict__ bfc,
                                                 float* __restrict__ out) {
  int t = threadIdx.x, b = t >> 6, o = t & 63;
  float acc = bfc[o];
  for (int f = 0; f < FEAT; ++f)
    acc = fmaf(pooled[b * FEAT + f], Wfc[f * OOUT + o], acc);
  out[b * OOUT + o] = acc;
}

extern "C" void kernel_launch(void* const* d_in, const int* in_sizes, int n_in,
                              void* d_out, int out_size, void* d_ws, size_t ws_size,
                              hipStream_t stream) {
  const float* x    = (const float*)d_in[0];
  const float* W1   = (const float*)d_in[1];
  const float* b1   = (const float*)d_in[2];
  const float* W2   = (const float*)d_in[3];
  const float* b2   = (const float*)d_in[4];
  const float* Wfc  = (const float*)d_in[5];
  const float* bfc  = (const float*)d_in[6];
  const int*   eraw = (const int*)d_in[7];
  int E = in_sizes[7] / 2;
  float* out = (float*)d_out;

  char* ws = (char*)d_ws;
  size_t off = 0;
  auto alloc = [&](size_t elems) -> void* {   // elems in 4-byte units
    void* p = ws + off * 4;
    off += (elems + 3) & ~(size_t)3;          // keep 16B alignment
    return p;
  };
  int*   flag      = (int*)alloc(4);
  int*   s32       = (int*)alloc(E);
  int*   d32       = (int*)alloc(E);
  int*   cnt       = (int*)alloc(NNODES);
  float* dinv      = (float*)alloc(NNODES);
  int*   row_start = (int*)alloc(NNODES + 1);
  int*   fill      = (int*)alloc(NNODES);
  int*   csr_src   = (int*)alloc(E);
  float* csr_norm  = (float*)alloc(E);
  unsigned short* w1hi = (unsigned short*)alloc(65536 / 2);
  unsigned short* w1lo = (unsigned short*)alloc(65536 / 2);
  unsigned short* w2hi = (unsigned short*)alloc(65536 / 2);
  unsigned short* w2lo = (unsigned short*)alloc(65536 / 2);
  unsigned short* hbf  = (unsigned short*)alloc((size_t)MPAD * FEAT / 2);    // padded GEMM out, bf16
  unsigned short* a1   = (unsigned short*)alloc((size_t)MROWS * FEAT / 2);   // agg1 out, bf16
  float* pp        = (float*)alloc((size_t)8 * NBLK * 64);                   // final-agg partials
  float* pooled    = (float*)alloc(BATCH * FEAT);

  int eg = (E + 255) / 256;
  detect_zero_kernel<<<1, 256, 0, stream>>>(eraw, flag, cnt, fill, E);
  convert_count_kernel<<<eg, 256, 0, stream>>>(eraw, flag, s32, d32, cnt, E);
  scan_dinv_kernel<<<1, 1024, 0, stream>>>(cnt, row_start, dinv, NNODES);
  scatter_kernel<<<eg, 256, 0, stream>>>(s32, d32, row_start, fill, dinv, csr_src, csr_norm, E);
  wprep_kernel<<<512, 256, 0, stream>>>(W1, W2, w1hi, w1lo, w2hi, w2lo);

  gemm_mfma<1><<<MPAD / 64, 256, 0, stream>>>(x, w1hi, w1lo, hbf);
  agg_kernel<0><<<NBLK * 8, 256, 0, stream>>>(hbf, row_start, csr_src, csr_norm, dinv, b1, a1, pp);
  gemm_mfma<0><<<MPAD / 64, 256, 0, stream>>>(a1, w2hi, w2lo, hbf);
  agg_kernel<1><<<NBLK * 8, 256, 0, stream>>>(hbf, row_start, csr_src, csr_norm, dinv, b2, a1, pp);
  pool_reduce<<<512, 256, 0, stream>>>(pp, pooled);
  fc_kernel<<<1, 128, 0, stream>>>(pooled, Wfc, bfc, out);
}

// Round 5
// 218.571 us; speedup vs baseline: 1.2608x; 1.2608x over previous
//
#include <hip/hip_runtime.h>

#define NNODES 20000
#define BATCH  2
#define FEAT   256
#define OOUT   64
#define PBLK   200
#define MROWS  (BATCH * NNODES)   // 40000
#define MPAD   40064              // 626 * 64

typedef short  bhalf8 __attribute__((ext_vector_type(8)));   // 8 bf16 in 4 VGPRs
typedef float  floatx4 __attribute__((ext_vector_type(4)));
typedef float  floatx2 __attribute__((ext_vector_type(2)));

// ---------- bf16 helpers ----------
__device__ __forceinline__ float bf2f(unsigned short u) {
  return __uint_as_float(((unsigned int)u) << 16);
}
__device__ __forceinline__ unsigned short f2bf(float f) {  // round-to-nearest-even
  unsigned int u = __float_as_uint(f);
  return (unsigned short)((u + 0x7fffu + ((u >> 16) & 1u)) >> 16);
}

// ---------- fp8 e4m3 helpers (HW converts, RNE) ----------
__device__ __forceinline__ unsigned int pack4_fp8(float a, float b, float c, float d) {
  int p = __builtin_amdgcn_cvt_pk_fp8_f32(a, b, 0, false);   // bytes 0,1
  p = __builtin_amdgcn_cvt_pk_fp8_f32(c, d, p, true);        // bytes 2,3
  return (unsigned int)p;
}

// ---------- detect edge dtype + zero cnt/fill (single block) ----------
__global__ __launch_bounds__(256) void detect_zero_kernel(const int* __restrict__ raw,
                                                          int* __restrict__ flag,
                                                          int* __restrict__ cnt,
                                                          int* __restrict__ fill, int E) {
  for (int i = threadIdx.x; i < NNODES; i += 256) { cnt[i] = 0; fill[i] = 0; }
  __shared__ int any;
  if (threadIdx.x == 0) any = 0;
  __syncthreads();
  int nchk = E < 2048 ? E : 2048;
  for (int i = threadIdx.x; i < nchk; i += blockDim.x)
    if (raw[2 * i + 1] != 0) any = 1;   // int64 high words are 0 (values < 20000)
  __syncthreads();
  if (threadIdx.x == 0) *flag = any;    // 1 => int32 layout, 0 => int64 layout
}

// ---------- convert + degree count ----------
__global__ void convert_count_kernel(const int* __restrict__ raw, const int* __restrict__ flag,
                                     int* __restrict__ s32, int* __restrict__ d32,
                                     int* __restrict__ cnt, int E) {
  int e = blockIdx.x * blockDim.x + threadIdx.x;
  if (e >= E) return;
  int s, d;
  if (*flag) { s = raw[e];     d = raw[E + e]; }
  else       { s = raw[2 * e]; d = raw[2 * (E + e)]; }
  s32[e] = s; d32[e] = d;
  atomicAdd(&cnt[d], 1);
}

// single-block scan over counts -> exclusive row_start; also computes dinv
__global__ __launch_bounds__(1024) void scan_dinv_kernel(const int* __restrict__ cnt,
                                                         int* __restrict__ row_start,
                                                         float* __restrict__ dinv, int n) {
  __shared__ int wsum[16];
  __shared__ int carry_s;
  int tid = threadIdx.x, lane = tid & 63, wv = tid >> 6;
  if (tid == 0) carry_s = 0;
  __syncthreads();
  for (int base = 0; base < n; base += 1024) {
    int v = (base + tid < n) ? cnt[base + tid] : 0;
    if (base + tid < n) dinv[base + tid] = 1.0f / sqrtf((float)(v + 1));
    int x = v;                              // inclusive wave scan
#pragma unroll
    for (int off = 1; off < 64; off <<= 1) {
      int t = __shfl_up(x, off);
      if (lane >= off) x += t;
    }
    if (lane == 63) wsum[wv] = x;
    __syncthreads();
    int carry = carry_s;
    if (wv == 0) {
      int s = (lane < 16) ? wsum[lane] : 0;
#pragma unroll
      for (int off = 1; off < 16; off <<= 1) {
        int t = __shfl_up(s, off);
        if (lane >= off) s += t;
      }
      if (lane < 16) wsum[lane] = s;
    }
    __syncthreads();
    int woff = wv ? wsum[wv - 1] : 0;
    int total = wsum[15];
    if (base + tid < n) row_start[base + tid] = carry + woff + x - v;
    __syncthreads();
    if (tid == 0) carry_s = carry + total;
  }
  if (tid == 0) row_start[n] = carry_s;
}

__global__ void scatter_kernel(const int* __restrict__ s32, const int* __restrict__ d32,
                               const int* __restrict__ row_start, int* __restrict__ fill,
                               const float* __restrict__ dinv,
                               int* __restrict__ csr_src, float* __restrict__ csr_norm, int E) {
  int e = blockIdx.x * blockDim.x + threadIdx.x;
  if (e >= E) return;
  int s = s32[e], d = d32[e];
  int p = row_start[d] + atomicAdd(&fill[d], 1);
  csr_src[p] = s;
  csr_norm[p] = dinv[s] * dinv[d];
}

// ---------- W prep: fp32 W[k][n] -> bf16 hi/lo, MFMA fragment order; blocks 0-255 -> W1, 256-511 -> W2
__global__ __launch_bounds__(256) void wprep_kernel(const float* __restrict__ W1,
                                                    const float* __restrict__ W2,
                                                    unsigned short* __restrict__ W1hi,
                                                    unsigned short* __restrict__ W1lo,
                                                    unsigned short* __restrict__ W2hi,
                                                    unsigned short* __restrict__ W2lo) {
  int which = blockIdx.x >> 8;
  int idx = (blockIdx.x & 255) * 256 + threadIdx.x;   // idx = k*256 + n
  const float* W = which ? W2 : W1;
  unsigned short* Whi = which ? W2hi : W1hi;
  unsigned short* Wlo = which ? W2lo : W1lo;
  int k = idx >> 8, n = idx & 255;
  float w = W[idx];
  unsigned short hi = f2bf(w);
  unsigned short lo = f2bf(w - bf2f(hi));
  int g = n >> 4, ln = n & 15;
  int ks = k >> 5, ch = (k >> 3) & 3, j = k & 7;
  int addr = ((ks * 16 + g) * 64 + ch * 16 + ln) * 8 + j;
  Whi[addr] = hi;
  Wlo[addr] = lo;
}

// ---------- MFMA GEMM: C[M,256] = A[M,256] @ W; A fp32 (layer1) or bf16 (layer2); C fp8 e4m3 ----------
// swapped operands: acc = mfma(W_frag, A_frag). Wave covers 32 rows x 128 cols:
// per K-step 16 ds_read_b128 feed 32 MFMAs (2:1), vs 1:1 in the 16x256 shape.
template <int AFP32>
__global__ __launch_bounds__(256) void gemm_mfma(const void* __restrict__ Av,
                                                 const unsigned short* __restrict__ Whi,
                                                 const unsigned short* __restrict__ Wlo,
                                                 unsigned int* __restrict__ C) {
  __shared__ unsigned short lds_arr[32768];   // 2 bufs x (hi 8192 + lo 8192) ushorts
  int tid = threadIdx.x, lane = tid & 63, wv = tid >> 6;
  int wrow = wv >> 1, wcol = wv & 1;
  int m0 = blockIdx.x * 64 + wrow * 32;
  int mr0 = m0 + (lane & 15);
  int mr1 = m0 + 16 + (lane & 15);
  if (mr0 >= MROWS) mr0 = MROWS - 1;          // clamp pad rows (output ignored)
  if (mr1 >= MROWS) mr1 = MROWS - 1;
  int kc = (lane >> 4) * 8;                   // k-chunk offset within BK=32

  const float* Af          = (const float*)Av;
  const unsigned short* Ab = (const unsigned short*)Av;

  floatx4 acc[2][8];
#pragma unroll
  for (int t = 0; t < 2; ++t)
#pragma unroll
    for (int g = 0; g < 8; ++g) acc[t][g] = (floatx4)(0.0f);

  bhalf8 st[8];  // staging regs: 4 hi + 4 lo chunks of 16B per thread

  auto stage_load = [&](int ks) {
#pragma unroll
    for (int i = 0; i < 4; ++i)
      st[i] = *(const bhalf8*)&Whi[(size_t)ks * 8192 + (i * 256 + tid) * 8];
#pragma unroll
    for (int i = 0; i < 4; ++i)
      st[4 + i] = *(const bhalf8*)&Wlo[(size_t)ks * 8192 + (i * 256 + tid) * 8];
  };
  auto stage_write = [&](int b) {
    unsigned short* base = &lds_arr[b * 16384];
#pragma unroll
    for (int i = 0; i < 4; ++i)
      *(bhalf8*)&base[(i * 256 + tid) * 8] = st[i];
#pragma unroll
    for (int i = 0; i < 4; ++i)
      *(bhalf8*)&base[8192 + (i * 256 + tid) * 8] = st[4 + i];
  };
  auto load_a = [&](int mrow, int ks) -> bhalf8 {
    bhalf8 r;
    if (AFP32) {
      const float* p = &Af[(size_t)mrow * FEAT + ks * 32 + kc];
      float4 u = *(const float4*)p;
      float4 v = *(const float4*)(p + 4);
      r[0] = (short)f2bf(u.x); r[1] = (short)f2bf(u.y);
      r[2] = (short)f2bf(u.z); r[3] = (short)f2bf(u.w);
      r[4] = (short)f2bf(v.x); r[5] = (short)f2bf(v.y);
      r[6] = (short)f2bf(v.z); r[7] = (short)f2bf(v.w);
    } else {
      r = *(const bhalf8*)&Ab[(size_t)mrow * FEAT + ks * 32 + kc];
    }
    return r;
  };

  stage_load(0);
  stage_write(0);
  __syncthreads();
  int cur = 0;
  for (int ks = 0; ks < 8; ++ks) {
    if (ks < 7) stage_load(ks + 1);           // global loads in flight under compute
    bhalf8 a0 = load_a(mr0, ks);
    bhalf8 a1 = load_a(mr1, ks);
    const unsigned short* bb = &lds_arr[cur * 16384];
#pragma unroll
    for (int g = 0; g < 8; ++g) {
      int gg = wcol * 8 + g;
      bhalf8 bh = *(const bhalf8*)&bb[gg * 512 + lane * 8];          // contiguous: conflict-free
      bhalf8 bl = *(const bhalf8*)&bb[8192 + gg * 512 + lane * 8];
      acc[0][g] = __builtin_amdgcn_mfma_f32_16x16x32_bf16(bh, a0, acc[0][g], 0, 0, 0);
      acc[0][g] = __builtin_amdgcn_mfma_f32_16x16x32_bf16(bl, a0, acc[0][g], 0, 0, 0);
      acc[1][g] = __builtin_amdgcn_mfma_f32_16x16x32_bf16(bh, a1, acc[1][g], 0, 0, 0);
      acc[1][g] = __builtin_amdgcn_mfma_f32_16x16x32_bf16(bl, a1, acc[1][g], 0, 0, 0);
    }
    if (ks < 7) stage_write(cur ^ 1);
    __syncthreads();
    cur ^= 1;
  }

  // D layout: m_local = lane&15, n_local = (lane>>4)*4 + reg; pack 4 cols -> 1 uint of fp8
  int nc = (lane >> 4) * 4;
#pragma unroll
  for (int t = 0; t < 2; ++t) {
    int om = m0 + t * 16 + (lane & 15);       // < MPAD, C is padded
#pragma unroll
    for (int g = 0; g < 8; ++g) {
      int col = (wcol * 8 + g) * 16 + nc;
      C[(size_t)om * 64 + (col >> 2)] =
          pack4_fp8(acc[t][g][0], acc[t][g][1], acc[t][g][2], acc[t][g][3]);
    }
  }
}

// ---------- aggregation: out[b,n,:] = bf16(relu(bias + dinv^2*h[n] + sum norm*h[src])) ----------
// h is fp8 e4m3 (64 uints per 256-feat row); accumulate fp32; out bf16.
__global__ __launch_bounds__(128) void agg_kernel(const unsigned int* __restrict__ h8,
                                                  const int* __restrict__ row_start,
                                                  const int* __restrict__ csr_src,
                                                  const float* __restrict__ csr_norm,
                                                  const float* __restrict__ dinv,
                                                  const float* __restrict__ bias,
                                                  unsigned short* __restrict__ out) {
  int n = blockIdx.x;
  int b = threadIdx.x >> 6;          // wave 0 -> batch 0, wave 1 -> batch 1
  int lane = threadIdx.x & 63;       // 4 feats per lane: c = lane*4
  const unsigned int* hb = h8 + (size_t)b * NNODES * 64;
  float di = dinv[n];
  float sn = di * di;
  unsigned int v = hb[(size_t)n * 64 + lane];
  floatx2 v01 = __builtin_amdgcn_cvt_pk_f32_fp8((int)v, false);
  floatx2 v23 = __builtin_amdgcn_cvt_pk_f32_fp8((int)v, true);
  float4 acc = make_float4(v01[0] * sn, v01[1] * sn, v23[0] * sn, v23[1] * sn);
  int s0 = row_start[n], s1 = row_start[n + 1];
  int i = s0;
  for (; i + 2 <= s1; i += 2) {
    int sa = csr_src[i], sb = csr_src[i + 1];
    float wa = csr_norm[i], wb = csr_norm[i + 1];
    unsigned int ma = hb[(size_t)sa * 64 + lane];
    unsigned int mb = hb[(size_t)sb * 64 + lane];
    floatx2 a01 = __builtin_amdgcn_cvt_pk_f32_fp8((int)ma, false);
    floatx2 a23 = __builtin_amdgcn_cvt_pk_f32_fp8((int)ma, true);
    floatx2 b01 = __builtin_amdgcn_cvt_pk_f32_fp8((int)mb, false);
    floatx2 b23 = __builtin_amdgcn_cvt_pk_f32_fp8((int)mb, true);
    acc.x = fmaf(wa, a01[0], acc.x);
    acc.y = fmaf(wa, a01[1], acc.y);
    acc.z = fmaf(wa, a23[0], acc.z);
    acc.w = fmaf(wa, a23[1], acc.w);
    acc.x = fmaf(wb, b01[0], acc.x);
    acc.y = fmaf(wb, b01[1], acc.y);
    acc.z = fmaf(wb, b23[0], acc.z);
    acc.w = fmaf(wb, b23[1], acc.w);
  }
  if (i < s1) {
    int s = csr_src[i];
    float w = csr_norm[i];
    unsigned int m = hb[(size_t)s * 64 + lane];
    floatx2 a01 = __builtin_amdgcn_cvt_pk_f32_fp8((int)m, false);
    floatx2 a23 = __builtin_amdgcn_cvt_pk_f32_fp8((int)m, true);
    acc.x = fmaf(w, a01[0], acc.x);
    acc.y = fmaf(w, a01[1], acc.y);
    acc.z = fmaf(w, a23[0], acc.z);
    acc.w = fmaf(w, a23[1], acc.w);
  }
  int c = lane * 4;
  float4 bi = *(const float4*)&bias[c];
  ushort4 o;
  o.x = f2bf(fmaxf(acc.x + bi.x, 0.0f));
  o.y = f2bf(fmaxf(acc.y + bi.y, 0.0f));
  o.z = f2bf(fmaxf(acc.z + bi.z, 0.0f));
  o.w = f2bf(fmaxf(acc.w + bi.w, 0.0f));
  *(ushort4*)&out[((size_t)b * NNODES + n) * FEAT + c] = o;
}

// ---------- pooling (two-stage deterministic) + FC ----------
__global__ __launch_bounds__(256) void pool_partial(const unsigned short* __restrict__ h2,
                                                    float* __restrict__ partials) {
  int blk = blockIdx.x;
  int c = threadIdx.x;
  int chunk = NNODES / PBLK;          // 100
  int n0 = blk * chunk;
  float s0 = 0.f, s1 = 0.f;
  for (int n = n0; n < n0 + chunk; ++n) {
    s0 += bf2f(h2[((size_t)0 * NNODES + n) * FEAT + c]);
    s1 += bf2f(h2[((size_t)1 * NNODES + n) * FEAT + c]);
  }
  partials[(blk * 2 + 0) * FEAT + c] = s0;
  partials[(blk * 2 + 1) * FEAT + c] = s1;
}

__global__ __launch_bounds__(256) void pool_fc(const float* __restrict__ partials,
                                               const float* __restrict__ Wfc, const float* __restrict__ bfc,
                                               float* __restrict__ out) {
  __shared__ float pooled[BATCH][FEAT];
  int t = threadIdx.x;  // channel
  float s0 = 0.f, s1 = 0.f;
  for (int p = 0; p < PBLK; ++p) {
    s0 += partials[(p * 2 + 0) * FEAT + t];
    s1 += partials[(p * 2 + 1) * FEAT + t];
  }
  pooled[0][t] = s0 / (float)NNODES;
  pooled[1][t] = s1 / (float)NNODES;
  __syncthreads();
  if (t < BATCH * OOUT) {
    int b = t >> 6, o = t & 63;
    float acc = bfc[o];
    for (int c2 = 0; c2 < FEAT; ++c2)
      acc = fmaf(pooled[b][c2], Wfc[c2 * OOUT + o], acc);
    out[b * OOUT + o] = acc;
  }
}

extern "C" void kernel_launch(void* const* d_in, const int* in_sizes, int n_in,
                              void* d_out, int out_size, void* d_ws, size_t ws_size,
                              hipStream_t stream) {
  const float* x    = (const float*)d_in[0];
  const float* W1   = (const float*)d_in[1];
  const float* b1   = (const float*)d_in[2];
  const float* W2   = (const float*)d_in[3];
  const float* b2   = (const float*)d_in[4];
  const float* Wfc  = (const float*)d_in[5];
  const float* bfc  = (const float*)d_in[6];
  const int*   eraw = (const int*)d_in[7];
  int E = in_sizes[7] / 2;
  float* out = (float*)d_out;

  char* ws = (char*)d_ws;
  size_t off = 0;
  auto alloc = [&](size_t elems) -> void* {   // elems in 4-byte units
    void* p = ws + off * 4;
    off += (elems + 3) & ~(size_t)3;          // keep 16B alignment
    return p;
  };
  int*   flag      = (int*)alloc(4);
  int*   s32       = (int*)alloc(E);
  int*   d32       = (int*)alloc(E);
  int*   cnt       = (int*)alloc(NNODES);
  float* dinv      = (float*)alloc(NNODES);
  int*   row_start = (int*)alloc(NNODES + 1);
  int*   fill      = (int*)alloc(NNODES);
  int*   csr_src   = (int*)alloc(E);
  float* csr_norm  = (float*)alloc(E);
  unsigned short* w1hi = (unsigned short*)alloc(65536 / 2);
  unsigned short* w1lo = (unsigned short*)alloc(65536 / 2);
  unsigned short* w2hi = (unsigned short*)alloc(65536 / 2);
  unsigned short* w2lo = (unsigned short*)alloc(65536 / 2);
  unsigned int*   h8   = (unsigned int*)alloc((size_t)MPAD * 64);            // fp8 GEMM out (padded)
  unsigned short* a1   = (unsigned short*)alloc((size_t)MROWS * FEAT / 2);   // agg out, bf16
  float* partials  = (float*)alloc((size_t)PBLK * BATCH * FEAT);

  int eg = (E + 255) / 256;
  detect_zero_kernel<<<1, 256, 0, stream>>>(eraw, flag, cnt, fill, E);
  convert_count_kernel<<<eg, 256, 0, stream>>>(eraw, flag, s32, d32, cnt, E);
  scan_dinv_kernel<<<1, 1024, 0, stream>>>(cnt, row_start, dinv, NNODES);
  scatter_kernel<<<eg, 256, 0, stream>>>(s32, d32, row_start, fill, dinv, csr_src, csr_norm, E);
  wprep_kernel<<<512, 256, 0, stream>>>(W1, W2, w1hi, w1lo, w2hi, w2lo);

  gemm_mfma<1><<<MPAD / 64, 256, 0, stream>>>(x, w1hi, w1lo, h8);
  agg_kernel<<<NNODES, 128, 0, stream>>>(h8, row_start, csr_src, csr_norm, dinv, b1, a1);
  gemm_mfma<0><<<MPAD / 64, 256, 0, stream>>>(a1, w2hi, w2lo, h8);
  agg_kernel<<<NNODES, 128, 0, stream>>>(h8, row_start, csr_src, csr_norm, dinv, b2, a1);
  pool_partial<<<PBLK, 256, 0, stream>>>(a1, partials);
  pool_fc<<<1, 256, 0, stream>>>(partials, Wfc, bfc, out);
}